// Round 3
// baseline (709.336 us; speedup 1.0000x reference)
//
#include <hip/hip_runtime.h>
#include <math.h>

#define NN 50000
#define NE 400000
#define FF 128
#define PD 384          // 3*F
#define NRBF 20
#define CUT 5.0f
#define EPSV 1e-8f
#define PI_F 3.14159265358979323846f

// ---------------------------------------------------------------------------
// Kernel 1: phi = silu(s @ W1 + b1) @ W2 + b2        (N x 384), fp32 vector
// Block: 256 threads, 64 nodes per block. LDS: s_tile + h_tile = 64KB.
// ---------------------------------------------------------------------------
__global__ __launch_bounds__(256) void phi_gemm(
    const float* __restrict__ s, const float* __restrict__ W1,
    const float* __restrict__ b1, const float* __restrict__ W2,
    const float* __restrict__ b2, float* __restrict__ phi)
{
    __shared__ float s_tile[64][FF];
    __shared__ float h_tile[64][FF];
    const int tid = threadIdx.x;
    const int node0 = blockIdx.x * 64;

    // load s tile (coalesced float4), zero-fill OOB rows
    for (int idx = tid; idx < 64 * 32; idx += 256) {
        int m = idx >> 5;
        int k4 = (idx & 31) << 2;
        int node = node0 + m;
        float4 val = make_float4(0.f, 0.f, 0.f, 0.f);
        if (node < NN) val = *(const float4*)(s + (size_t)node * FF + k4);
        *(float4*)&s_tile[m][k4] = val;
    }
    __syncthreads();

    const int k4 = (tid & 31) << 2;   // channel group 0..124
    const int mg = tid >> 5;          // 0..7

    // phase A: h = silu(s @ W1 + b1)
    float4 acc[8];
#pragma unroll
    for (int mm = 0; mm < 8; mm++) acc[mm] = make_float4(0.f, 0.f, 0.f, 0.f);
    for (int i = 0; i < FF; i++) {
        float4 w = *(const float4*)(W1 + i * FF + k4);
#pragma unroll
        for (int mm = 0; mm < 8; mm++) {
            float sv = s_tile[mg + mm * 8][i];          // LDS broadcast
            acc[mm].x = fmaf(sv, w.x, acc[mm].x);
            acc[mm].y = fmaf(sv, w.y, acc[mm].y);
            acc[mm].z = fmaf(sv, w.z, acc[mm].z);
            acc[mm].w = fmaf(sv, w.w, acc[mm].w);
        }
    }
    {
        float4 bb = *(const float4*)(b1 + k4);
#pragma unroll
        for (int mm = 0; mm < 8; mm++) {
            float4 a = acc[mm];
            a.x += bb.x; a.y += bb.y; a.z += bb.z; a.w += bb.w;
            a.x = a.x / (1.f + __expf(-a.x));
            a.y = a.y / (1.f + __expf(-a.y));
            a.z = a.z / (1.f + __expf(-a.z));
            a.w = a.w / (1.f + __expf(-a.w));
            *(float4*)&h_tile[mg + mm * 8][k4] = a;
        }
    }
    __syncthreads();

    // phase B: phi = h @ W2 + b2  (3 passes over the 384 output channels)
    for (int jp = 0; jp < 3; jp++) {
        const int j4 = jp * FF + k4;
        float4 acc2[8];
#pragma unroll
        for (int mm = 0; mm < 8; mm++) acc2[mm] = make_float4(0.f, 0.f, 0.f, 0.f);
        for (int k = 0; k < FF; k++) {
            float4 w = *(const float4*)(W2 + k * PD + j4);
#pragma unroll
            for (int mm = 0; mm < 8; mm++) {
                float hv = h_tile[mg + mm * 8][k];      // LDS broadcast
                acc2[mm].x = fmaf(hv, w.x, acc2[mm].x);
                acc2[mm].y = fmaf(hv, w.y, acc2[mm].y);
                acc2[mm].z = fmaf(hv, w.z, acc2[mm].z);
                acc2[mm].w = fmaf(hv, w.w, acc2[mm].w);
            }
        }
        float4 b2v = *(const float4*)(b2 + j4);
#pragma unroll
        for (int mm = 0; mm < 8; mm++) {
            int node = node0 + mg + mm * 8;
            if (node < NN) {
                float4 a = acc2[mm];
                a.x += b2v.x; a.y += b2v.y; a.z += b2v.z; a.w += b2v.w;
                *(float4*)(phi + (size_t)node * PD + j4) = a;
            }
        }
    }
}

// ---------------------------------------------------------------------------
// CSR build: count -> scan -> fill
// ---------------------------------------------------------------------------
__global__ void count_kernel(const float* __restrict__ r, int* __restrict__ counts)
{
    int e = blockIdx.x * 256 + threadIdx.x;
    if (e < NE) {
        int j = (int)r[(size_t)e * 5 + 1];
        atomicAdd(&counts[j], 1);
    }
}

__global__ __launch_bounds__(1024) void scan_kernel(
    const int* __restrict__ counts, int* __restrict__ offsets, int* __restrict__ cursor)
{
    const int PER = (NN + 1023) / 1024;   // 49
    const int tid = threadIdx.x;
    const int start = tid * PER;

    int local = 0;
    for (int k = 0; k < PER; k++) {
        int i = start + k;
        if (i < NN) local += counts[i];
    }
    // wave-level inclusive scan of per-thread totals
    int lane = tid & 63, wv = tid >> 6;
    int vsc = local;
#pragma unroll
    for (int off = 1; off < 64; off <<= 1) {
        int t = __shfl_up(vsc, off);
        if (lane >= off) vsc += t;
    }
    __shared__ int wsum[16], wpre[16];
    if (lane == 63) wsum[wv] = vsc;
    __syncthreads();
    if (tid == 0) {
        int run = 0;
        for (int w = 0; w < 16; w++) { wpre[w] = run; run += wsum[w]; }
    }
    __syncthreads();
    int run = (vsc - local) + wpre[wv];   // exclusive prefix for this strip
    for (int k = 0; k < PER; k++) {
        int i = start + k;
        if (i < NN) {
            offsets[i] = run;
            cursor[i]  = run;
            run += counts[i];
        }
    }
    if (tid == 1023) offsets[NN] = run;   // strip 1023 is empty: run == total == NE
}

__global__ void fill_kernel(const float* __restrict__ r, int* __restrict__ cursor,
                            int* __restrict__ eids)
{
    int e = blockIdx.x * 256 + threadIdx.x;
    if (e < NE) {
        int j = (int)r[(size_t)e * 5 + 1];
        int p = atomicAdd(&cursor[j], 1);
        eids[p] = e;
    }
}

// ---------------------------------------------------------------------------
// Kernel 2: node-centric edge accumulation + output. Block = 1 node, 128 thr.
// Thread f owns output channel f; Wr columns {f, F+f, 2F+f} live in registers.
// gather idx == scatter idx, so all accumulation is node-local (no atomics).
// ---------------------------------------------------------------------------
__global__ __launch_bounds__(128) void node_kernel(
    const float* __restrict__ r, const float* __restrict__ v,
    const float* __restrict__ phi, const float* __restrict__ Wr,
    const float* __restrict__ br, const int* __restrict__ offsets,
    const int* __restrict__ eids, float* __restrict__ out_v,
    float* __restrict__ out_s)
{
    const int i = blockIdx.x;
    const int f = threadIdx.x;
    const int e0 = offsets[i], e1 = offsets[i + 1];

    float wra[NRBF], wrb[NRBF], wrc[NRBF];
#pragma unroll
    for (int n = 0; n < NRBF; n++) {
        wra[n] = Wr[n * PD + f];
        wrb[n] = Wr[n * PD + FF + f];
        wrc[n] = Wr[n * PD + 2 * FF + f];
    }
    const float xba = br[f], xbb = br[FF + f], xbc = br[2 * FF + f];

    float aW0 = 0.f, aW1 = 0.f, aD0 = 0.f, aD1 = 0.f, aD2 = 0.f;

    __shared__ __align__(16) float rbf_s[24];
    __shared__ float rv_s[3];

    for (int ep = e0; ep < e1; ++ep) {
        int e = eids[ep];
        if (f < 3) rv_s[f] = r[(size_t)e * 5 + 2 + f];
        __syncthreads();
        float rx = rv_s[0], ry = rv_s[1], rz = rv_s[2];
        float nz = fabsf(rz);
        if (f < NRBF) rbf_s[f] = sinf((float)(f + 1) * (PI_F / CUT) * nz) / (nz + EPSV);
        float inv = 1.f / (sqrtf(rx * rx + ry * ry + rz * rz) + EPSV);
        float dx = rx * inv, dy = ry * inv, dz = rz * inv;
        __syncthreads();

        float rb[NRBF];
#pragma unroll
        for (int n = 0; n < NRBF; n += 4) {
            float4 q = *(const float4*)&rbf_s[n];
            rb[n] = q.x; rb[n + 1] = q.y; rb[n + 2] = q.z; rb[n + 3] = q.w;
        }
        float xa = xba, xb = xbb, xc = xbc;
#pragma unroll
        for (int n = 0; n < NRBF; n++) {
            xa = fmaf(rb[n], wra[n], xa);
            xb = fmaf(rb[n], wrb[n], xb);
            xc = fmaf(rb[n], wrc[n], xc);
        }
        float Wa = (xa < CUT) ? 0.5f * (__cosf((PI_F / CUT) * xa) + 1.f) : 0.f;
        float Wb = (xb < CUT) ? 0.5f * (__cosf((PI_F / CUT) * xb) + 1.f) : 0.f;
        float Wc = (xc < CUT) ? 0.5f * (__cosf((PI_F / CUT) * xc) + 1.f) : 0.f;
        aW0 += Wa;
        aW1 += Wb;
        aD0 = fmaf(Wc, dx, aD0);
        aD1 = fmaf(Wc, dy, aD1);
        aD2 = fmaf(Wc, dz, aD2);
    }

    const float pa = phi[(size_t)i * PD + f];
    const float pb = phi[(size_t)i * PD + FF + f];
    const float pc = phi[(size_t)i * PD + 2 * FF + f];
    const float s1s = pa * aW0;

    const float v0 = v[(size_t)i * PD + f * 3 + 0];
    const float v1 = v[(size_t)i * PD + f * 3 + 1];
    const float v2 = v[(size_t)i * PD + f * 3 + 2];

    __shared__ float ov[PD];
    ov[f * 3 + 0] = fmaf(v0, s1s, pc * aD0);
    ov[f * 3 + 1] = fmaf(v1, s1s, pc * aD1);
    ov[f * 3 + 2] = fmaf(v2, s1s, pc * aD2);
    __syncthreads();
    out_v[(size_t)i * PD + f]          = ov[f];
    out_v[(size_t)i * PD + FF + f]     = ov[FF + f];
    out_v[(size_t)i * PD + 2 * FF + f] = ov[2 * FF + f];
    out_s[(size_t)i * FF + f] = pb * aW1;
}

// ---------------------------------------------------------------------------
extern "C" void kernel_launch(void* const* d_in, const int* in_sizes, int n_in,
                              void* d_out, int out_size, void* d_ws, size_t ws_size,
                              hipStream_t stream)
{
    const float* v  = (const float*)d_in[0];
    const float* s  = (const float*)d_in[1];
    const float* r  = (const float*)d_in[2];
    const float* W1 = (const float*)d_in[3];
    const float* b1 = (const float*)d_in[4];
    const float* W2 = (const float*)d_in[5];
    const float* b2 = (const float*)d_in[6];
    const float* Wr = (const float*)d_in[7];
    const float* br = (const float*)d_in[8];

    float* out_v = (float*)d_out;
    float* out_s = out_v + (size_t)NN * PD;

    char* ws = (char*)d_ws;
    size_t off = 0;
    float* phi    = (float*)(ws + off); off += (size_t)NN * PD * 4;
    int*   counts = (int*)(ws + off);   off += (size_t)NN * 4;
    int*   cursor = (int*)(ws + off);   off += (size_t)NN * 4;
    int*   offsets= (int*)(ws + off);   off += (size_t)(NN + 1) * 4;
    int*   eids   = (int*)(ws + off);   off += (size_t)NE * 4;

    hipMemsetAsync(counts, 0, (size_t)NN * 4, stream);
    phi_gemm<<<(NN + 63) / 64, 256, 0, stream>>>(s, W1, b1, W2, b2, phi);
    count_kernel<<<(NE + 255) / 256, 256, 0, stream>>>(r, counts);
    scan_kernel<<<1, 1024, 0, stream>>>(counts, offsets, cursor);
    fill_kernel<<<(NE + 255) / 256, 256, 0, stream>>>(r, cursor, eids);
    node_kernel<<<NN, 128, 0, stream>>>(r, v, phi, Wr, br, offsets, eids,
                                        out_v, out_s);
}

// Round 4
// 682.143 us; speedup vs baseline: 1.0399x; 1.0399x over previous
//
#include <hip/hip_runtime.h>
#include <math.h>

#define NN 50000
#define NE 400000
#define FF 128
#define PD 384          // 3*F
#define NRBF 20
#define CUT 5.0f
#define EPSV 1e-8f
#define PI_F 3.14159265358979323846f
#define FEATW 24        // 20 rbf + 3 dir + 1 pad
#define LDP (FF + 4)    // padded LDS row (float4-aligned, 2-way max bank alias)

// ---------------------------------------------------------------------------
// Kernel 1: phi = silu(s @ W1 + b1) @ W2 + b2   (N x 384), fp32 vector
// v2: 32 nodes/block, 256 threads = (rg 0..15) x (cg 0..15).
// Thread owns rows {rg, rg+16} and cols cg*8..cg*8+7  -> 16 acc.
// Per k-iter: 2 LDS broadcast reads : 16 FMA (was 8:32).
// ---------------------------------------------------------------------------
__global__ __launch_bounds__(256) void phi_gemm(
    const float* __restrict__ s, const float* __restrict__ W1,
    const float* __restrict__ b1, const float* __restrict__ W2,
    const float* __restrict__ b2, float* __restrict__ phi)
{
    __shared__ float s_tile[32][LDP];
    __shared__ float h_tile[32][LDP];
    const int tid = threadIdx.x;
    const int node0 = blockIdx.x * 32;

    // load s tile (coalesced float4), zero-fill OOB rows
    for (int idx = tid; idx < 32 * 32; idx += 256) {
        int m = idx >> 5;
        int k4 = (idx & 31) << 2;
        int node = node0 + m;
        float4 val = make_float4(0.f, 0.f, 0.f, 0.f);
        if (node < NN) val = *(const float4*)(s + (size_t)node * FF + k4);
        *(float4*)&s_tile[m][k4] = val;
    }
    __syncthreads();

    const int cg = tid & 15;          // col group: cols c0..c0+7
    const int rg = tid >> 4;          // row group: rows rg, rg+16
    const int c0 = cg << 3;

    // phase A: h = silu(s @ W1 + b1)
    float a0[8], a1[8];
#pragma unroll
    for (int c = 0; c < 8; c++) { a0[c] = 0.f; a1[c] = 0.f; }
#pragma unroll 4
    for (int k = 0; k < FF; k++) {
        float4 wA = *(const float4*)(W1 + k * FF + c0);
        float4 wB = *(const float4*)(W1 + k * FF + c0 + 4);
        float s0 = s_tile[rg][k];
        float s1 = s_tile[rg + 16][k];
        a0[0] = fmaf(s0, wA.x, a0[0]); a0[1] = fmaf(s0, wA.y, a0[1]);
        a0[2] = fmaf(s0, wA.z, a0[2]); a0[3] = fmaf(s0, wA.w, a0[3]);
        a0[4] = fmaf(s0, wB.x, a0[4]); a0[5] = fmaf(s0, wB.y, a0[5]);
        a0[6] = fmaf(s0, wB.z, a0[6]); a0[7] = fmaf(s0, wB.w, a0[7]);
        a1[0] = fmaf(s1, wA.x, a1[0]); a1[1] = fmaf(s1, wA.y, a1[1]);
        a1[2] = fmaf(s1, wA.z, a1[2]); a1[3] = fmaf(s1, wA.w, a1[3]);
        a1[4] = fmaf(s1, wB.x, a1[4]); a1[5] = fmaf(s1, wB.y, a1[5]);
        a1[6] = fmaf(s1, wB.z, a1[6]); a1[7] = fmaf(s1, wB.w, a1[7]);
    }
    {
        float4 bA = *(const float4*)(b1 + c0);
        float4 bB = *(const float4*)(b1 + c0 + 4);
        float bb[8] = { bA.x, bA.y, bA.z, bA.w, bB.x, bB.y, bB.z, bB.w };
        float4 h0a, h0b, h1a, h1b;
        float t0[8], t1[8];
#pragma unroll
        for (int c = 0; c < 8; c++) {
            float x0 = a0[c] + bb[c];
            float x1 = a1[c] + bb[c];
            t0[c] = x0 / (1.f + __expf(-x0));
            t1[c] = x1 / (1.f + __expf(-x1));
        }
        h0a = make_float4(t0[0], t0[1], t0[2], t0[3]);
        h0b = make_float4(t0[4], t0[5], t0[6], t0[7]);
        h1a = make_float4(t1[0], t1[1], t1[2], t1[3]);
        h1b = make_float4(t1[4], t1[5], t1[6], t1[7]);
        *(float4*)&h_tile[rg][c0]          = h0a;
        *(float4*)&h_tile[rg][c0 + 4]      = h0b;
        *(float4*)&h_tile[rg + 16][c0]     = h1a;
        *(float4*)&h_tile[rg + 16][c0 + 4] = h1b;
    }
    __syncthreads();

    // phase B: phi = h @ W2 + b2  (3 passes over the 384 output channels)
    const bool row1ok = (node0 + 16 + rg) < NN;   // row rg always valid (NN%32==16)
    for (int jp = 0; jp < 3; jp++) {
        const float* W2p = W2 + jp * FF + c0;
        float b0[8], b1v[8];
#pragma unroll
        for (int c = 0; c < 8; c++) { b0[c] = 0.f; b1v[c] = 0.f; }
#pragma unroll 4
        for (int k = 0; k < FF; k++) {
            float4 wA = *(const float4*)(W2p + (size_t)k * PD);
            float4 wB = *(const float4*)(W2p + (size_t)k * PD + 4);
            float h0 = h_tile[rg][k];
            float h1 = h_tile[rg + 16][k];
            b0[0] = fmaf(h0, wA.x, b0[0]); b0[1] = fmaf(h0, wA.y, b0[1]);
            b0[2] = fmaf(h0, wA.z, b0[2]); b0[3] = fmaf(h0, wA.w, b0[3]);
            b0[4] = fmaf(h0, wB.x, b0[4]); b0[5] = fmaf(h0, wB.y, b0[5]);
            b0[6] = fmaf(h0, wB.z, b0[6]); b0[7] = fmaf(h0, wB.w, b0[7]);
            b1v[0] = fmaf(h1, wA.x, b1v[0]); b1v[1] = fmaf(h1, wA.y, b1v[1]);
            b1v[2] = fmaf(h1, wA.z, b1v[2]); b1v[3] = fmaf(h1, wA.w, b1v[3]);
            b1v[4] = fmaf(h1, wB.x, b1v[4]); b1v[5] = fmaf(h1, wB.y, b1v[5]);
            b1v[6] = fmaf(h1, wB.z, b1v[6]); b1v[7] = fmaf(h1, wB.w, b1v[7]);
        }
        float4 bA = *(const float4*)(b2 + jp * FF + c0);
        float4 bB = *(const float4*)(b2 + jp * FF + c0 + 4);
        float bb[8] = { bA.x, bA.y, bA.z, bA.w, bB.x, bB.y, bB.z, bB.w };
        float* dst0 = phi + (size_t)(node0 + rg) * PD + jp * FF + c0;
        *(float4*)(dst0)     = make_float4(b0[0] + bb[0], b0[1] + bb[1],
                                           b0[2] + bb[2], b0[3] + bb[3]);
        *(float4*)(dst0 + 4) = make_float4(b0[4] + bb[4], b0[5] + bb[5],
                                           b0[6] + bb[6], b0[7] + bb[7]);
        if (row1ok) {
            float* dst1 = phi + (size_t)(node0 + 16 + rg) * PD + jp * FF + c0;
            *(float4*)(dst1)     = make_float4(b1v[0] + bb[0], b1v[1] + bb[1],
                                               b1v[2] + bb[2], b1v[3] + bb[3]);
            *(float4*)(dst1 + 4) = make_float4(b1v[4] + bb[4], b1v[5] + bb[5],
                                               b1v[6] + bb[6], b1v[7] + bb[7]);
        }
    }
}

// ---------------------------------------------------------------------------
// CSR build: count -> scan -> fill(+edge features, written in CSR order)
// ---------------------------------------------------------------------------
__global__ void count_kernel(const float* __restrict__ r, int* __restrict__ counts)
{
    int e = blockIdx.x * 256 + threadIdx.x;
    if (e < NE) {
        int j = (int)r[(size_t)e * 5 + 1];
        atomicAdd(&counts[j], 1);
    }
}

__global__ __launch_bounds__(1024) void scan_kernel(
    const int* __restrict__ counts, int* __restrict__ offsets, int* __restrict__ cursor)
{
    const int PER = (NN + 1023) / 1024;   // 49
    const int tid = threadIdx.x;
    const int start = tid * PER;

    int local = 0;
    for (int k = 0; k < PER; k++) {
        int i = start + k;
        if (i < NN) local += counts[i];
    }
    int lane = tid & 63, wv = tid >> 6;
    int vsc = local;
#pragma unroll
    for (int off = 1; off < 64; off <<= 1) {
        int t = __shfl_up(vsc, off);
        if (lane >= off) vsc += t;
    }
    __shared__ int wsum[16], wpre[16];
    if (lane == 63) wsum[wv] = vsc;
    __syncthreads();
    if (tid == 0) {
        int run = 0;
        for (int w = 0; w < 16; w++) { wpre[w] = run; run += wsum[w]; }
    }
    __syncthreads();
    int run = (vsc - local) + wpre[wv];   // exclusive prefix for this strip
    for (int k = 0; k < PER; k++) {
        int i = start + k;
        if (i < NN) {
            offsets[i] = run;
            cursor[i]  = run;
            run += counts[i];
        }
    }
    if (tid == 1023) offsets[NN] = run;   // strip 1023 empty: run == total == NE
}

// Per edge: claim CSR slot p, compute rbf[20] + dirn[3], write feat[p][24].
// Writing in CSR order makes node-side reads contiguous and kills eids.
__global__ void fill_edge_kernel(const float* __restrict__ r,
                                 int* __restrict__ cursor,
                                 float* __restrict__ feat)
{
    int e = blockIdx.x * 256 + threadIdx.x;
    if (e >= NE) return;
    const float* re = r + (size_t)e * 5;
    int j = (int)re[1];
    float rx = re[2], ry = re[3], rz = re[4];
    int p = atomicAdd(&cursor[j], 1);

    float nz = fabsf(rz);
    float inv = 1.f / (sqrtf(rx * rx + ry * ry + rz * rz) + EPSV);
    float rcp = 1.f / (nz + EPSV);
    float arg = (PI_F / CUT) * nz;

    float fbuf[FEATW];
#pragma unroll
    for (int n = 0; n < NRBF; n++)
        fbuf[n] = sinf((float)(n + 1) * arg) * rcp;
    fbuf[20] = rx * inv;
    fbuf[21] = ry * inv;
    fbuf[22] = rz * inv;
    fbuf[23] = 0.f;

    float* dst = feat + (size_t)p * FEATW;
#pragma unroll
    for (int q = 0; q < 6; q++)
        *(float4*)(dst + q * 4) = *(const float4*)(fbuf + q * 4);
}

// ---------------------------------------------------------------------------
// Kernel 2: node-centric accumulation. Block = 1 node, 128 threads.
// Edge features precomputed in CSR order -> batch-stage 16 edges into LDS
// with one sync pair, then pure register FMA per edge (no per-edge sync,
// no trig on the critical path). Thread f owns channels {f, F+f, 2F+f}.
// ---------------------------------------------------------------------------
__global__ __launch_bounds__(128) void node_kernel(
    const float* __restrict__ v, const float* __restrict__ phi,
    const float* __restrict__ Wr, const float* __restrict__ br,
    const int* __restrict__ offsets, const float* __restrict__ feat,
    float* __restrict__ out_v, float* __restrict__ out_s)
{
    const int i = blockIdx.x;
    const int f = threadIdx.x;
    const int e0 = offsets[i], e1 = offsets[i + 1];

    float wra[NRBF], wrb[NRBF], wrc[NRBF];
#pragma unroll
    for (int n = 0; n < NRBF; n++) {
        wra[n] = Wr[n * PD + f];
        wrb[n] = Wr[n * PD + FF + f];
        wrc[n] = Wr[n * PD + 2 * FF + f];
    }
    const float xba = br[f], xbb = br[FF + f], xbc = br[2 * FF + f];

    float aW0 = 0.f, aW1 = 0.f, aD0 = 0.f, aD1 = 0.f, aD2 = 0.f;

    __shared__ __align__(16) float lds_feat[16][FEATW];

    for (int base = e0; base < e1; base += 16) {
        int nb = min(16, e1 - base);
        __syncthreads();                       // lds_feat reuse guard
        if (f < nb * 6) {
            int slot = f / 6, q = f % 6;
            *(float4*)&lds_feat[slot][q * 4] =
                *(const float4*)(feat + (size_t)(base + slot) * FEATW + q * 4);
        }
        __syncthreads();

#pragma unroll 2
        for (int jj = 0; jj < nb; jj++) {
            float rb[NRBF];
#pragma unroll
            for (int q = 0; q < 5; q++) {
                float4 t = *(const float4*)&lds_feat[jj][q * 4];
                rb[q * 4]     = t.x; rb[q * 4 + 1] = t.y;
                rb[q * 4 + 2] = t.z; rb[q * 4 + 3] = t.w;
            }
            float4 dv = *(const float4*)&lds_feat[jj][20];

            float xa = xba, xb = xbb, xc = xbc;
#pragma unroll
            for (int n = 0; n < NRBF; n++) {
                xa = fmaf(rb[n], wra[n], xa);
                xb = fmaf(rb[n], wrb[n], xb);
                xc = fmaf(rb[n], wrc[n], xc);
            }
            float Wa = (xa < CUT) ? 0.5f * (__cosf((PI_F / CUT) * xa) + 1.f) : 0.f;
            float Wb = (xb < CUT) ? 0.5f * (__cosf((PI_F / CUT) * xb) + 1.f) : 0.f;
            float Wc = (xc < CUT) ? 0.5f * (__cosf((PI_F / CUT) * xc) + 1.f) : 0.f;
            aW0 += Wa;
            aW1 += Wb;
            aD0 = fmaf(Wc, dv.x, aD0);
            aD1 = fmaf(Wc, dv.y, aD1);
            aD2 = fmaf(Wc, dv.z, aD2);
        }
    }

    const float pa = phi[(size_t)i * PD + f];
    const float pb = phi[(size_t)i * PD + FF + f];
    const float pc = phi[(size_t)i * PD + 2 * FF + f];
    const float s1s = pa * aW0;

    const float v0 = v[(size_t)i * PD + f * 3 + 0];
    const float v1 = v[(size_t)i * PD + f * 3 + 1];
    const float v2 = v[(size_t)i * PD + f * 3 + 2];

    __shared__ float ov[PD];
    ov[f * 3 + 0] = fmaf(v0, s1s, pc * aD0);
    ov[f * 3 + 1] = fmaf(v1, s1s, pc * aD1);
    ov[f * 3 + 2] = fmaf(v2, s1s, pc * aD2);
    __syncthreads();
    out_v[(size_t)i * PD + f]          = ov[f];
    out_v[(size_t)i * PD + FF + f]     = ov[FF + f];
    out_v[(size_t)i * PD + 2 * FF + f] = ov[2 * FF + f];
    out_s[(size_t)i * FF + f] = pb * aW1;
}

// ---------------------------------------------------------------------------
extern "C" void kernel_launch(void* const* d_in, const int* in_sizes, int n_in,
                              void* d_out, int out_size, void* d_ws, size_t ws_size,
                              hipStream_t stream)
{
    const float* v  = (const float*)d_in[0];
    const float* s  = (const float*)d_in[1];
    const float* r  = (const float*)d_in[2];
    const float* W1 = (const float*)d_in[3];
    const float* b1 = (const float*)d_in[4];
    const float* W2 = (const float*)d_in[5];
    const float* b2 = (const float*)d_in[6];
    const float* Wr = (const float*)d_in[7];
    const float* br = (const float*)d_in[8];

    float* out_v = (float*)d_out;
    float* out_s = out_v + (size_t)NN * PD;

    char* ws = (char*)d_ws;
    size_t off = 0;
    float* phi    = (float*)(ws + off); off += (size_t)NN * PD * 4;      // 76.8 MB
    float* feat   = (float*)(ws + off); off += (size_t)NE * FEATW * 4;   // 38.4 MB
    int*   counts = (int*)(ws + off);   off += (size_t)NN * 4;
    int*   cursor = (int*)(ws + off);   off += (size_t)NN * 4;
    int*   offsets= (int*)(ws + off);   off += (size_t)(NN + 1) * 4;

    hipMemsetAsync(counts, 0, (size_t)NN * 4, stream);
    phi_gemm<<<(NN + 31) / 32, 256, 0, stream>>>(s, W1, b1, W2, b2, phi);
    count_kernel<<<(NE + 255) / 256, 256, 0, stream>>>(r, counts);
    scan_kernel<<<1, 1024, 0, stream>>>(counts, offsets, cursor);
    fill_edge_kernel<<<(NE + 255) / 256, 256, 0, stream>>>(r, cursor, feat);
    node_kernel<<<NN, 128, 0, stream>>>(v, phi, Wr, br, offsets, feat,
                                        out_v, out_s);
}

// Round 7
// 533.452 us; speedup vs baseline: 1.3297x; 1.2787x over previous
//
#include <hip/hip_runtime.h>
#include <math.h>

#define NN 50000
#define NE 400000
#define FF 128
#define PD 384          // 3*F
#define NRBF 20
#define CUT 5.0f
#define EPSV 1e-8f
#define PI_F 3.14159265358979323846f
#define FEATW 24        // 20 rbf + 3 dir + 1 pad
#define HLP 144         // H LDS row pitch in bf16 (128 + 16 pad)

typedef __attribute__((ext_vector_type(8))) short bf16x8;
typedef __attribute__((ext_vector_type(4))) float f32x4;

// float -> bf16 bits, round-to-nearest-even (finite inputs)
static __device__ __forceinline__ short f2bf(float x)
{
    union { float f; unsigned u; } c; c.f = x;
    unsigned r = c.u + 0x7FFFu + ((c.u >> 16) & 1u);
    return (short)(r >> 16);
}

// ---------------------------------------------------------------------------
// Prep: WT1[c][k] = bf16(W1[k][c])  (128x128), WT2[c][k] = bf16(W2[k][c]) (384x128)
// ---------------------------------------------------------------------------
__global__ void prep_wt(const float* __restrict__ W1, const float* __restrict__ W2,
                        short* __restrict__ WT1, short* __restrict__ WT2)
{
    int idx = blockIdx.x * 256 + threadIdx.x;
    if (idx < FF * FF) {
        int c = idx >> 7, k = idx & 127;
        WT1[c * FF + k] = f2bf(W1[k * FF + c]);
    } else if (idx < FF * FF + PD * FF) {
        int i2 = idx - FF * FF;
        int c = i2 >> 7, k = i2 & 127;
        WT2[c * FF + k] = f2bf(W2[(size_t)k * PD + c]);
    }
}

// ---------------------------------------------------------------------------
// Kernel 1: phi = silu(s @ W1 + b1) @ W2 + b2 via bf16 MFMA (16x16x32).
// Block: 256 thr = 4 waves; 64 node-rows/block; wave w owns rows 16w..16w+15.
// Fragment layouts (m89/m97-verified):
//   A: lane holds A[l&15][(l>>4)*8 + j], j=0..7  (8 contiguous k)
//   B: lane holds B[(l>>4)*8 + j][l&15]  -> from WT[c][k]: 8 contiguous k
//   D: lane,reg q -> D[(l>>4)*4 + q][l&15]
// ---------------------------------------------------------------------------
__global__ __launch_bounds__(256) void phi_mfma(
    const float* __restrict__ s, const short* __restrict__ WT1,
    const float* __restrict__ b1, const short* __restrict__ WT2,
    const float* __restrict__ b2, float* __restrict__ phi)
{
    __shared__ short Hl[64][HLP];

    const int tid  = threadIdx.x;
    const int wv   = tid >> 6;          // 0..3
    const int lane = tid & 63;
    const int lr   = lane & 15;         // row (A/D-col) index within tile
    const int lk   = lane >> 4;         // 0..3 k-group
    const int node0 = blockIdx.x * 64;
    const int rowA  = node0 + wv * 16 + lr;   // A-side global row
    const bool rowAok = rowA < NN;

    // ---- load A-fragments of s (4 chunks of K=32), fp32 -> bf16 ----
    bf16x8 a[4];
#pragma unroll
    for (int kk = 0; kk < 4; kk++) {
        const float* sp = s + (size_t)rowA * FF + kk * 32 + lk * 8;
        float4 u0 = make_float4(0.f, 0.f, 0.f, 0.f);
        float4 u1 = make_float4(0.f, 0.f, 0.f, 0.f);
        if (rowAok) { u0 = *(const float4*)sp; u1 = *(const float4*)(sp + 4); }
        bf16x8 t;
        t[0] = f2bf(u0.x); t[1] = f2bf(u0.y); t[2] = f2bf(u0.z); t[3] = f2bf(u0.w);
        t[4] = f2bf(u1.x); t[5] = f2bf(u1.y); t[6] = f2bf(u1.z); t[7] = f2bf(u1.w);
        a[kk] = t;
    }

    // ---- GEMM1: H = silu(s @ W1 + b1), 8 col-tiles ----
    f32x4 acc1[8];
#pragma unroll
    for (int ct = 0; ct < 8; ct++) acc1[ct] = (f32x4){0.f, 0.f, 0.f, 0.f};

#pragma unroll
    for (int ct = 0; ct < 8; ct++) {
        const short* wp = WT1 + (ct * 16 + lr) * FF + lk * 8;
#pragma unroll
        for (int kk = 0; kk < 4; kk++) {
            bf16x8 b = *(const bf16x8*)(wp + kk * 32);
            acc1[ct] = __builtin_amdgcn_mfma_f32_16x16x32_bf16(a[kk], b, acc1[ct], 0, 0, 0);
        }
    }

    // ---- silu + stage H to LDS (bf16) ----
#pragma unroll
    for (int ct = 0; ct < 8; ct++) {
        const int col = ct * 16 + lr;
        const float bias = b1[col];
#pragma unroll
        for (int q = 0; q < 4; q++) {
            float x = acc1[ct][q] + bias;
            float h = x / (1.f + __expf(-x));
            Hl[wv * 16 + lk * 4 + q][col] = f2bf(h);
        }
    }
    __syncthreads();

    // ---- A2-fragments of H from LDS ----
    bf16x8 a2[4];
#pragma unroll
    for (int kk = 0; kk < 4; kk++)
        a2[kk] = *(const bf16x8*)&Hl[wv * 16 + lr][kk * 32 + lk * 8];

    // ---- GEMM2: phi = H @ W2 + b2, 24 col-tiles ----
    const int rowD0 = node0 + wv * 16 + lk * 4;   // D-side global row base
    for (int ct = 0; ct < 24; ct++) {
        f32x4 acc = {0.f, 0.f, 0.f, 0.f};
        const short* wp = WT2 + (ct * 16 + lr) * FF + lk * 8;
#pragma unroll
        for (int kk = 0; kk < 4; kk++) {
            bf16x8 b = *(const bf16x8*)(wp + kk * 32);
            acc = __builtin_amdgcn_mfma_f32_16x16x32_bf16(a2[kk], b, acc, 0, 0, 0);
        }
        const int col = ct * 16 + lr;
        const float bias = b2[col];
#pragma unroll
        for (int q = 0; q < 4; q++) {
            int row = rowD0 + q;
            if (row < NN) phi[(size_t)row * PD + col] = acc[q] + bias;
        }
    }
}

// ---------------------------------------------------------------------------
// CSR build: count -> scan -> fill(+edge features, written in CSR order)
// ---------------------------------------------------------------------------
__global__ void count_kernel(const float* __restrict__ r, int* __restrict__ counts)
{
    int e = blockIdx.x * 256 + threadIdx.x;
    if (e < NE) {
        int j = (int)r[(size_t)e * 5 + 1];
        atomicAdd(&counts[j], 1);
    }
}

__global__ __launch_bounds__(1024) void scan_kernel(
    const int* __restrict__ counts, int* __restrict__ offsets, int* __restrict__ cursor)
{
    const int PER = (NN + 1023) / 1024;   // 49
    const int tid = threadIdx.x;
    const int start = tid * PER;

    int local = 0;
    for (int k = 0; k < PER; k++) {
        int i = start + k;
        if (i < NN) local += counts[i];
    }
    int lane = tid & 63, wv = tid >> 6;
    int vsc = local;
#pragma unroll
    for (int off = 1; off < 64; off <<= 1) {
        int t = __shfl_up(vsc, off);
        if (lane >= off) vsc += t;
    }
    __shared__ int wsum[16], wpre[16];
    if (lane == 63) wsum[wv] = vsc;
    __syncthreads();
    if (tid == 0) {
        int run = 0;
        for (int w = 0; w < 16; w++) { wpre[w] = run; run += wsum[w]; }
    }
    __syncthreads();
    int run = (vsc - local) + wpre[wv];   // exclusive prefix for this strip
    for (int k = 0; k < PER; k++) {
        int i = start + k;
        if (i < NN) {
            offsets[i] = run;
            cursor[i]  = run;
            run += counts[i];
        }
    }
    if (tid == 1023) offsets[NN] = run;   // strip 1023 empty: run == total == NE
}

__global__ void fill_edge_kernel(const float* __restrict__ r,
                                 int* __restrict__ cursor,
                                 float* __restrict__ feat)
{
    int e = blockIdx.x * 256 + threadIdx.x;
    if (e >= NE) return;
    const float* re = r + (size_t)e * 5;
    int j = (int)re[1];
    float rx = re[2], ry = re[3], rz = re[4];
    int p = atomicAdd(&cursor[j], 1);

    float nz = fabsf(rz);
    float inv = 1.f / (sqrtf(rx * rx + ry * ry + rz * rz) + EPSV);
    float rcp = 1.f / (nz + EPSV);
    float arg = (PI_F / CUT) * nz;

    float fbuf[FEATW];
#pragma unroll
    for (int n = 0; n < NRBF; n++)
        fbuf[n] = sinf((float)(n + 1) * arg) * rcp;
    fbuf[20] = rx * inv;
    fbuf[21] = ry * inv;
    fbuf[22] = rz * inv;
    fbuf[23] = 0.f;

    float* dst = feat + (size_t)p * FEATW;
#pragma unroll
    for (int q = 0; q < 6; q++)
        *(float4*)(dst + q * 4) = *(const float4*)(fbuf + q * 4);
}

// ---------------------------------------------------------------------------
// Kernel 2: node-centric accumulation. Block = 1 node, 128 threads.
// ---------------------------------------------------------------------------
__global__ __launch_bounds__(128) void node_kernel(
    const float* __restrict__ v, const float* __restrict__ phi,
    const float* __restrict__ Wr, const float* __restrict__ br,
    const int* __restrict__ offsets, const float* __restrict__ feat,
    float* __restrict__ out_v, float* __restrict__ out_s)
{
    const int i = blockIdx.x;
    const int f = threadIdx.x;
    const int e0 = offsets[i], e1 = offsets[i + 1];

    float wra[NRBF], wrb[NRBF], wrc[NRBF];
#pragma unroll
    for (int n = 0; n < NRBF; n++) {
        wra[n] = Wr[n * PD + f];
        wrb[n] = Wr[n * PD + FF + f];
        wrc[n] = Wr[n * PD + 2 * FF + f];
    }
    const float xba = br[f], xbb = br[FF + f], xbc = br[2 * FF + f];

    float aW0 = 0.f, aW1 = 0.f, aD0 = 0.f, aD1 = 0.f, aD2 = 0.f;

    __shared__ __align__(16) float lds_feat[16][FEATW];

    for (int base = e0; base < e1; base += 16) {
        int nb = min(16, e1 - base);
        __syncthreads();                       // lds_feat reuse guard
        if (f < nb * 6) {
            int slot = f / 6, q = f % 6;
            *(float4*)&lds_feat[slot][q * 4] =
                *(const float4*)(feat + (size_t)(base + slot) * FEATW + q * 4);
        }
        __syncthreads();

#pragma unroll 2
        for (int jj = 0; jj < nb; jj++) {
            float rb[NRBF];
#pragma unroll
            for (int q = 0; q < 5; q++) {
                float4 t = *(const float4*)&lds_feat[jj][q * 4];
                rb[q * 4]     = t.x; rb[q * 4 + 1] = t.y;
                rb[q * 4 + 2] = t.z; rb[q * 4 + 3] = t.w;
            }
            float4 dv = *(const float4*)&lds_feat[jj][20];

            float xa = xba, xb = xbb, xc = xbc;
#pragma unroll
            for (int n = 0; n < NRBF; n++) {
                xa = fmaf(rb[n], wra[n], xa);
                xb = fmaf(rb[n], wrb[n], xb);
                xc = fmaf(rb[n], wrc[n], xc);
            }
            float Wa = (xa < CUT) ? 0.5f * (__cosf((PI_F / CUT) * xa) + 1.f) : 0.f;
            float Wb = (xb < CUT) ? 0.5f * (__cosf((PI_F / CUT) * xb) + 1.f) : 0.f;
            float Wc = (xc < CUT) ? 0.5f * (__cosf((PI_F / CUT) * xc) + 1.f) : 0.f;
            aW0 += Wa;
            aW1 += Wb;
            aD0 = fmaf(Wc, dv.x, aD0);
            aD1 = fmaf(Wc, dv.y, aD1);
            aD2 = fmaf(Wc, dv.z, aD2);
        }
    }

    const float pa = phi[(size_t)i * PD + f];
    const float pb = phi[(size_t)i * PD + FF + f];
    const float pc = phi[(size_t)i * PD + 2 * FF + f];
    const float s1s = pa * aW0;

    const float v0 = v[(size_t)i * PD + f * 3 + 0];
    const float v1 = v[(size_t)i * PD + f * 3 + 1];
    const float v2 = v[(size_t)i * PD + f * 3 + 2];

    __shared__ float ov[PD];
    ov[f * 3 + 0] = fmaf(v0, s1s, pc * aD0);
    ov[f * 3 + 1] = fmaf(v1, s1s, pc * aD1);
    ov[f * 3 + 2] = fmaf(v2, s1s, pc * aD2);
    __syncthreads();
    out_v[(size_t)i * PD + f]          = ov[f];
    out_v[(size_t)i * PD + FF + f]     = ov[FF + f];
    out_v[(size_t)i * PD + 2 * FF + f] = ov[2 * FF + f];
    out_s[(size_t)i * FF + f] = pb * aW1;
}

// ---------------------------------------------------------------------------
extern "C" void kernel_launch(void* const* d_in, const int* in_sizes, int n_in,
                              void* d_out, int out_size, void* d_ws, size_t ws_size,
                              hipStream_t stream)
{
    const float* v  = (const float*)d_in[0];
    const float* s  = (const float*)d_in[1];
    const float* r  = (const float*)d_in[2];
    const float* W1 = (const float*)d_in[3];
    const float* b1 = (const float*)d_in[4];
    const float* W2 = (const float*)d_in[5];
    const float* b2 = (const float*)d_in[6];
    const float* Wr = (const float*)d_in[7];
    const float* br = (const float*)d_in[8];

    float* out_v = (float*)d_out;
    float* out_s = out_v + (size_t)NN * PD;

    char* ws = (char*)d_ws;
    size_t off = 0;
    float* phi    = (float*)(ws + off); off += (size_t)NN * PD * 4;      // 76.8 MB
    float* feat   = (float*)(ws + off); off += (size_t)NE * FEATW * 4;   // 38.4 MB
    int*   counts = (int*)(ws + off);   off += (size_t)NN * 4;
    int*   cursor = (int*)(ws + off);   off += (size_t)NN * 4;
    int*   offsets= (int*)(ws + off);   off += (size_t)(NN + 1) * 4;
    short* WT1    = (short*)(ws + off); off += (size_t)FF * FF * 2;      // 32 KB
    short* WT2    = (short*)(ws + off); off += (size_t)PD * FF * 2;      // 96 KB

    hipMemsetAsync(counts, 0, (size_t)NN * 4, stream);
    prep_wt<<<(FF * FF + PD * FF + 255) / 256, 256, 0, stream>>>(W1, W2, WT1, WT2);
    phi_mfma<<<(NN + 63) / 64, 256, 0, stream>>>(s, WT1, b1, WT2, b2, phi);
    count_kernel<<<(NE + 255) / 256, 256, 0, stream>>>(r, counts);
    scan_kernel<<<1, 1024, 0, stream>>>(counts, offsets, cursor);
    fill_edge_kernel<<<(NE + 255) / 256, 256, 0, stream>>>(r, cursor, feat);
    node_kernel<<<NN, 128, 0, stream>>>(v, phi, Wr, br, offsets, feat,
                                        out_v, out_s);
}

// Round 9
// 431.659 us; speedup vs baseline: 1.6433x; 1.2358x over previous
//
#include <hip/hip_runtime.h>
#include <math.h>

#define NN 50000
#define NE 400000
#define FF 128
#define PD 384          // 3*F
#define NRBF 20
#define CUT 5.0f
#define EPSV 1e-8f
#define PI_F 3.14159265358979323846f
#define FEATW 24        // 20 rbf + 3 dir + 1 pad
#define HLP 144         // H LDS row pitch in bf16 (128 + 16 pad)
#define SCH 1024        // scan chunk
#define NB ((NN + SCH - 1) / SCH)   // 49 scan blocks
#define GN 16           // nodes per node_kernel block
#define WEDGE 192       // staged edge window per group

typedef __attribute__((ext_vector_type(8))) short bf16x8;
typedef __attribute__((ext_vector_type(4))) float f32x4;

// float -> bf16 bits, round-to-nearest-even (finite inputs)
static __device__ __forceinline__ short f2bf(float x)
{
    union { float f; unsigned u; } c; c.f = x;
    unsigned r = c.u + 0x7FFFu + ((c.u >> 16) & 1u);
    return (short)(r >> 16);
}

// ---------------------------------------------------------------------------
// Prep: pack W1/W2 into MFMA B-fragment order.
// frag index = ct*4+kk; lane holds B[k0+j][ct*16+(lane&15)], k0=kk*32+(lane>>4)*8.
// WT1p: 8 ct  -> 32 frags * 64 lanes * 8 bf16 (32 KB)
// WT2p: 24 ct -> 96 frags * 64 lanes * 8 bf16 (96 KB)
// ---------------------------------------------------------------------------
__global__ void prep_wt(const float* __restrict__ W1, const float* __restrict__ W2,
                        short* __restrict__ WT1p, short* __restrict__ WT2p)
{
    int idx = blockIdx.x * 256 + threadIdx.x;
    if (idx < 32 * 64) {
        int frag = idx >> 6, lane = idx & 63;
        int ct = frag >> 2, kk = frag & 3;
        int c  = ct * 16 + (lane & 15);
        int k0 = kk * 32 + (lane >> 4) * 8;
        short* dst = WT1p + (size_t)idx * 8;
#pragma unroll
        for (int j = 0; j < 8; j++)
            dst[j] = f2bf(W1[(size_t)(k0 + j) * FF + c]);
    } else if (idx < 32 * 64 + 96 * 64) {
        int id2 = idx - 32 * 64;
        int frag = id2 >> 6, lane = id2 & 63;
        int ct = frag >> 2, kk = frag & 3;
        int c  = ct * 16 + (lane & 15);
        int k0 = kk * 32 + (lane >> 4) * 8;
        short* dst = WT2p + (size_t)id2 * 8;
#pragma unroll
        for (int j = 0; j < 8; j++)
            dst[j] = f2bf(W2[(size_t)(k0 + j) * PD + c]);
    }
}

// ---------------------------------------------------------------------------
// Kernel 1: phi = silu(s @ W1 + b1) @ W2 + b2 via bf16 MFMA (16x16x32).
// B-fragments read from packed layout: one contiguous 1KB load per wave.
// ---------------------------------------------------------------------------
__global__ __launch_bounds__(256) void phi_mfma(
    const float* __restrict__ s, const short* __restrict__ WT1p,
    const float* __restrict__ b1, const short* __restrict__ WT2p,
    const float* __restrict__ b2, float* __restrict__ phi)
{
    __shared__ short Hl[64][HLP];

    const int tid  = threadIdx.x;
    const int wv   = tid >> 6;          // 0..3
    const int lane = tid & 63;
    const int lr   = lane & 15;
    const int lk   = lane >> 4;         // 0..3
    const int node0 = blockIdx.x * 64;
    const int rowA  = node0 + wv * 16 + lr;
    const bool rowAok = rowA < NN;

    // ---- load A-fragments of s (4 chunks of K=32), fp32 -> bf16 ----
    bf16x8 a[4];
#pragma unroll
    for (int kk = 0; kk < 4; kk++) {
        const float* sp = s + (size_t)rowA * FF + kk * 32 + lk * 8;
        float4 u0 = make_float4(0.f, 0.f, 0.f, 0.f);
        float4 u1 = make_float4(0.f, 0.f, 0.f, 0.f);
        if (rowAok) { u0 = *(const float4*)sp; u1 = *(const float4*)(sp + 4); }
        bf16x8 t;
        t[0] = f2bf(u0.x); t[1] = f2bf(u0.y); t[2] = f2bf(u0.z); t[3] = f2bf(u0.w);
        t[4] = f2bf(u1.x); t[5] = f2bf(u1.y); t[6] = f2bf(u1.z); t[7] = f2bf(u1.w);
        a[kk] = t;
    }

    // ---- GEMM1: H = silu(s @ W1 + b1), 8 col-tiles ----
    f32x4 acc1[8];
#pragma unroll
    for (int ct = 0; ct < 8; ct++) acc1[ct] = (f32x4){0.f, 0.f, 0.f, 0.f};
#pragma unroll
    for (int ct = 0; ct < 8; ct++) {
#pragma unroll
        for (int kk = 0; kk < 4; kk++) {
            bf16x8 b = *(const bf16x8*)(WT1p + ((size_t)(ct * 4 + kk) * 64 + lane) * 8);
            acc1[ct] = __builtin_amdgcn_mfma_f32_16x16x32_bf16(a[kk], b, acc1[ct], 0, 0, 0);
        }
    }

    // ---- silu + stage H to LDS (bf16) ----
#pragma unroll
    for (int ct = 0; ct < 8; ct++) {
        const int col = ct * 16 + lr;
        const float bias = b1[col];
#pragma unroll
        for (int q = 0; q < 4; q++) {
            float x = acc1[ct][q] + bias;
            float h = x / (1.f + __expf(-x));
            Hl[wv * 16 + lk * 4 + q][col] = f2bf(h);
        }
    }
    __syncthreads();

    // ---- A2-fragments of H from LDS ----
    bf16x8 a2[4];
#pragma unroll
    for (int kk = 0; kk < 4; kk++)
        a2[kk] = *(const bf16x8*)&Hl[wv * 16 + lr][kk * 32 + lk * 8];

    // ---- GEMM2: phi = H @ W2 + b2, 24 col-tiles ----
    const int rowD0 = node0 + wv * 16 + lk * 4;
    for (int ct = 0; ct < 24; ct++) {
        f32x4 acc = {0.f, 0.f, 0.f, 0.f};
#pragma unroll
        for (int kk = 0; kk < 4; kk++) {
            bf16x8 b = *(const bf16x8*)(WT2p + ((size_t)(ct * 4 + kk) * 64 + lane) * 8);
            acc = __builtin_amdgcn_mfma_f32_16x16x32_bf16(a2[kk], b, acc, 0, 0, 0);
        }
        const int col = ct * 16 + lr;
        const float bias = b2[col];
#pragma unroll
        for (int q = 0; q < 4; q++) {
            int row = rowD0 + q;
            if (row < NN) phi[(size_t)row * PD + col] = acc[q] + bias;
        }
    }
}

// ---------------------------------------------------------------------------
// CSR build: count -> 3-phase coalesced scan -> fill(+edge features)
// ---------------------------------------------------------------------------
__global__ void count_kernel(const float* __restrict__ r, int* __restrict__ counts)
{
    int e = blockIdx.x * 256 + threadIdx.x;
    if (e < NE) {
        int j = (int)r[(size_t)e * 5 + 1];
        atomicAdd(&counts[j], 1);
    }
}

// per-chunk exclusive scan; thread owns 4 contiguous ints (int4, coalesced)
__global__ __launch_bounds__(256) void scan1(
    const int* __restrict__ counts, int* __restrict__ offsets, int* __restrict__ bsum)
{
    const int t = threadIdx.x;
    const int base = blockIdx.x * SCH + t * 4;
    int4 c = make_int4(0, 0, 0, 0);
    if (base + 3 < NN) c = *(const int4*)(counts + base);
    else {
        if (base     < NN) c.x = counts[base];
        if (base + 1 < NN) c.y = counts[base + 1];
        if (base + 2 < NN) c.z = counts[base + 2];
    }
    int s0 = c.x, s1 = s0 + c.y, s2 = s1 + c.z, s3 = s2 + c.w;
    int lane = t & 63, wv = t >> 6;
    int inc = s3;
#pragma unroll
    for (int o = 1; o < 64; o <<= 1) {
        int u = __shfl_up(inc, o);
        if (lane >= o) inc += u;
    }
    __shared__ int ws[4];
    if (lane == 63) ws[wv] = inc;
    __syncthreads();
    int wp = 0;
    for (int w = 0; w < wv; w++) wp += ws[w];
    int ex = wp + inc - s3;                 // block-local exclusive prefix
    int4 o4 = make_int4(ex, ex + s0, ex + s1, ex + s2);
    if (base + 3 < NN) *(int4*)(offsets + base) = o4;
    else {
        if (base     < NN) offsets[base]     = o4.x;
        if (base + 1 < NN) offsets[base + 1] = o4.y;
        if (base + 2 < NN) offsets[base + 2] = o4.z;
    }
    __syncthreads();
    if (t == 0) bsum[blockIdx.x] = ws[0] + ws[1] + ws[2] + ws[3];
}

// single-wave scan of the 49 block sums
__global__ void scan2(const int* __restrict__ bsum, int* __restrict__ bpre,
                      int* __restrict__ offsets)
{
    int t = threadIdx.x;                    // 64 threads
    int vl = (t < NB) ? bsum[t] : 0;
    int inc = vl;
#pragma unroll
    for (int o = 1; o < 64; o <<= 1) {
        int u = __shfl_up(inc, o);
        if (t >= o) inc += u;
    }
    if (t < NB) bpre[t] = inc - vl;
    if (t == 63) offsets[NN] = inc;         // grand total == NE
}

// add block prefix; also materialize cursor
__global__ __launch_bounds__(256) void scan3(
    int* __restrict__ offsets, int* __restrict__ cursor, const int* __restrict__ bpre)
{
    const int t = threadIdx.x;
    const int base = blockIdx.x * SCH + t * 4;
    const int add = bpre[blockIdx.x];
    if (base + 3 < NN) {
        int4 o = *(const int4*)(offsets + base);
        o.x += add; o.y += add; o.z += add; o.w += add;
        *(int4*)(offsets + base) = o;
        *(int4*)(cursor  + base) = o;
    } else {
#pragma unroll
        for (int k = 0; k < 4; k++) {
            if (base + k < NN) {
                int x = offsets[base + k] + add;
                offsets[base + k] = x;
                cursor[base + k]  = x;
            }
        }
    }
}

__global__ void fill_edge_kernel(const float* __restrict__ r,
                                 int* __restrict__ cursor,
                                 float* __restrict__ feat)
{
    int e = blockIdx.x * 256 + threadIdx.x;
    if (e >= NE) return;
    const float* re = r + (size_t)e * 5;
    int j = (int)re[1];
    float rx = re[2], ry = re[3], rz = re[4];
    int p = atomicAdd(&cursor[j], 1);

    float nz = fabsf(rz);
    float inv = 1.f / (sqrtf(rx * rx + ry * ry + rz * rz) + EPSV);
    float rcp = 1.f / (nz + EPSV);
    float arg = (PI_F / CUT) * nz;

    float fbuf[FEATW];
#pragma unroll
    for (int n = 0; n < NRBF; n++)
        fbuf[n] = sinf((float)(n + 1) * arg) * rcp;
    fbuf[20] = rx * inv;
    fbuf[21] = ry * inv;
    fbuf[22] = rz * inv;
    fbuf[23] = 0.f;

    float* dst = feat + (size_t)p * FEATW;
#pragma unroll
    for (int q = 0; q < 6; q++)
        *(float4*)(dst + q * 4) = *(const float4*)(fbuf + q * 4);
}

// ---------------------------------------------------------------------------
// Kernel 2: node-group accumulation. Block = GN=16 nodes, 128 threads.
// Wr preload amortized over the group; group edge window staged once
// (1 sync); no per-node syncs (direct coalesced epilogue stores).
// ---------------------------------------------------------------------------
__global__ __launch_bounds__(128) void node_kernel(
    const float* __restrict__ v, const float* __restrict__ phi,
    const float* __restrict__ Wr, const float* __restrict__ br,
    const int* __restrict__ offsets, const float* __restrict__ feat,
    float* __restrict__ out_v, float* __restrict__ out_s)
{
    const int f  = threadIdx.x;
    const int i0 = blockIdx.x * GN;

    __shared__ int offs[GN + 1];
    __shared__ __align__(16) float lf[WEDGE][FEATW];

    if (f <= GN) offs[f] = offsets[i0 + f];
    __syncthreads();

    const int eBase = offs[0];
    const int nSt = min(offs[GN] - eBase, WEDGE);
    for (int idx = f; idx < nSt * 6; idx += 128) {
        int sl = idx / 6, q = idx % 6;
        *(float4*)&lf[sl][q * 4] =
            *(const float4*)(feat + (size_t)(eBase + sl) * FEATW + q * 4);
    }

    float wra[NRBF], wrb[NRBF], wrc[NRBF];
#pragma unroll
    for (int n = 0; n < NRBF; n++) {
        wra[n] = Wr[n * PD + f];
        wrb[n] = Wr[n * PD + FF + f];
        wrc[n] = Wr[n * PD + 2 * FF + f];
    }
    const float xba = br[f], xbb = br[FF + f], xbc = br[2 * FF + f];
    __syncthreads();

    for (int nd = 0; nd < GN; nd++) {
        const int e0 = offs[nd], e1 = offs[nd + 1];
        float aW0 = 0.f, aW1 = 0.f, aD0 = 0.f, aD1 = 0.f, aD2 = 0.f;

        for (int ep = e0; ep < e1; ++ep) {
            int rel = ep - eBase;
            float rb[NRBF];
            float4 dv;
            if (rel < WEDGE) {
#pragma unroll
                for (int q = 0; q < 5; q++) {
                    float4 t = *(const float4*)&lf[rel][q * 4];
                    rb[q * 4]     = t.x; rb[q * 4 + 1] = t.y;
                    rb[q * 4 + 2] = t.z; rb[q * 4 + 3] = t.w;
                }
                dv = *(const float4*)&lf[rel][20];
            } else {            // rare overflow path: broadcast global reads
                const float* fp = feat + (size_t)ep * FEATW;
#pragma unroll
                for (int q = 0; q < 5; q++) {
                    float4 t = *(const float4*)(fp + q * 4);
                    rb[q * 4]     = t.x; rb[q * 4 + 1] = t.y;
                    rb[q * 4 + 2] = t.z; rb[q * 4 + 3] = t.w;
                }
                dv = *(const float4*)(fp + 20);
            }

            float xa = xba, xb = xbb, xc = xbc;
#pragma unroll
            for (int n = 0; n < NRBF; n++) {
                xa = fmaf(rb[n], wra[n], xa);
                xb = fmaf(rb[n], wrb[n], xb);
                xc = fmaf(rb[n], wrc[n], xc);
            }
            float Wa = (xa < CUT) ? 0.5f * (__cosf((PI_F / CUT) * xa) + 1.f) : 0.f;
            float Wb = (xb < CUT) ? 0.5f * (__cosf((PI_F / CUT) * xb) + 1.f) : 0.f;
            float Wc = (xc < CUT) ? 0.5f * (__cosf((PI_F / CUT) * xc) + 1.f) : 0.f;
            aW0 += Wa;
            aW1 += Wb;
            aD0 = fmaf(Wc, dv.x, aD0);
            aD1 = fmaf(Wc, dv.y, aD1);
            aD2 = fmaf(Wc, dv.z, aD2);
        }

        const int i = i0 + nd;
        const float pa = phi[(size_t)i * PD + f];
        const float pb = phi[(size_t)i * PD + FF + f];
        const float pc = phi[(size_t)i * PD + 2 * FF + f];
        const float s1s = pa * aW0;
        const float* vp = v + (size_t)i * PD + f * 3;
        float* op = out_v + (size_t)i * PD + f * 3;
        op[0] = fmaf(vp[0], s1s, pc * aD0);
        op[1] = fmaf(vp[1], s1s, pc * aD1);
        op[2] = fmaf(vp[2], s1s, pc * aD2);
        out_s[(size_t)i * FF + f] = pb * aW1;
    }
}

// ---------------------------------------------------------------------------
extern "C" void kernel_launch(void* const* d_in, const int* in_sizes, int n_in,
                              void* d_out, int out_size, void* d_ws, size_t ws_size,
                              hipStream_t stream)
{
    const float* v  = (const float*)d_in[0];
    const float* s  = (const float*)d_in[1];
    const float* r  = (const float*)d_in[2];
    const float* W1 = (const float*)d_in[3];
    const float* b1 = (const float*)d_in[4];
    const float* W2 = (const float*)d_in[5];
    const float* b2 = (const float*)d_in[6];
    const float* Wr = (const float*)d_in[7];
    const float* br = (const float*)d_in[8];

    float* out_v = (float*)d_out;
    float* out_s = out_v + (size_t)NN * PD;

    char* ws = (char*)d_ws;
    size_t off = 0;
    float* phi    = (float*)(ws + off); off += (size_t)NN * PD * 4;      // 76.8 MB
    float* feat   = (float*)(ws + off); off += (size_t)NE * FEATW * 4;   // 38.4 MB
    int*   counts = (int*)(ws + off);   off += (size_t)NN * 4;
    int*   cursor = (int*)(ws + off);   off += (size_t)NN * 4;
    int*   offsets= (int*)(ws + off);   off += (size_t)(NN + 1) * 4;
    int*   bsum   = (int*)(ws + off);   off += (size_t)64 * 4;
    int*   bpre   = (int*)(ws + off);   off += (size_t)64 * 4;
    short* WT1p   = (short*)(ws + off); off += (size_t)32 * 64 * 8 * 2;  // 32 KB
    short* WT2p   = (short*)(ws + off); off += (size_t)96 * 64 * 8 * 2;  // 96 KB

    hipMemsetAsync(counts, 0, (size_t)NN * 4, stream);
    prep_wt<<<32, 256, 0, stream>>>(W1, W2, WT1p, WT2p);
    phi_mfma<<<(NN + 63) / 64, 256, 0, stream>>>(s, WT1p, b1, WT2p, b2, phi);
    count_kernel<<<(NE + 255) / 256, 256, 0, stream>>>(r, counts);
    scan1<<<NB, 256, 0, stream>>>(counts, offsets, bsum);
    scan2<<<1, 64, 0, stream>>>(bsum, bpre, offsets);
    scan3<<<NB, 256, 0, stream>>>(offsets, cursor, bpre);
    fill_edge_kernel<<<(NE + 255) / 256, 256, 0, stream>>>(r, cursor, feat);
    node_kernel<<<NN / GN, 128, 0, stream>>>(v, phi, Wr, br, offsets, feat,
                                             out_v, out_s);
}